// Round 14
// baseline (71.047 us; speedup 1.0000x reference)
//
#include <hip/hip_runtime.h>
#include <hip/hip_bf16.h>
#include <math.h>

#define B 4
#define T 128
#define S 512
#define H 512
// 2*log2(e): folds tanh's 2x and e->2 base change into the projection epilogue
#define QK_SCALE 2.8853900817779268f

// Hardware exp2 (v_exp_f32). Fallback = native exp path, never OCML-precise.
#if defined(__has_builtin)
#if __has_builtin(__builtin_amdgcn_exp2f)
#define EXP2F(x) __builtin_amdgcn_exp2f(x)
#else
#define EXP2F(x) __expf((x) * 0.6931471805599453f)
#endif
#else
#define EXP2F(x) __expf((x) * 0.6931471805599453f)
#endif

typedef __attribute__((ext_vector_type(8))) short bf16x8;
typedef __attribute__((ext_vector_type(4))) float f32x4;

__device__ __forceinline__ short f2b(float x) {   // f32 -> bf16 RNE
    unsigned int u = __float_as_uint(x);
    u += 0x7fffu + ((u >> 16) & 1u);
    return (short)(u >> 16);
}
__device__ __forceinline__ float fast_tanh(float x) {
    float e = __expf(2.0f * x);
    float r = __builtin_amdgcn_rcpf(e + 1.0f);
    return 1.0f - 2.0f * r;
}

// ---- phase 1: cvt inputs to bf16 (1152 blocks) ----
__global__ __launch_bounds__(256) void cvt_all(
    const float* __restrict__ q, const float* __restrict__ Ws,
    const float* __restrict__ Wh, const float* __restrict__ Wo,
    const float* __restrict__ enc,
    short* __restrict__ qb, short* __restrict__ wsb, short* __restrict__ whb,
    short* __restrict__ wob, short* __restrict__ eb) {
    size_t i = ((size_t)blockIdx.x * 256 + threadIdx.x) * 8;
    const float* src; short* dst; size_t off;
    if (i < 262144)        { src = q;   dst = qb;  off = i; }
    else if (i < 524288)   { src = Ws;  dst = wsb; off = i - 262144; }
    else if (i < 786432)   { src = Wh;  dst = whb; off = i - 524288; }
    else if (i < 1310720)  { src = Wo;  dst = wob; off = i - 786432; }
    else                   { src = enc; dst = eb;  off = i - 1310720; }
    float4 a = *(const float4*)(src + off);
    float4 b = *(const float4*)(src + off + 4);
    ushort4 o0 = make_ushort4((unsigned short)f2b(a.x), (unsigned short)f2b(a.y),
                              (unsigned short)f2b(a.z), (unsigned short)f2b(a.w));
    ushort4 o1 = make_ushort4((unsigned short)f2b(b.x), (unsigned short)f2b(b.y),
                              (unsigned short)f2b(b.z), (unsigned short)f2b(b.w));
    *(ushort4*)(dst + off) = o0;
    *(ushort4*)(dst + off + 4) = o1;
}

// ---- phase 2: mega wave-GEMM: 2560 one-wave 32x32 jobs ----
//   jobs [0,256):     Eq = exp2(q@Ws^T * QKS)            -> qe   (f32)
//   jobs [256,1280):  Ek = exp2(enc@Wh^T * QKS)          -> ke   (f32)  [masked tiles skip]
//   jobs [1280,2304): EWT[b][o][s] = bf16(Wo1@enc_b^T)   -> ewt  (bf16) [masked s-tiles skip]
//   jobs [2304,2560): QW = q@Wo2^T                       -> qw   (f32)
// Associativity: ((U/Z)@enc)@Wo1 == (U@EWT)/Z -> ctx stage & encT eliminated.
__global__ __launch_bounds__(64) void proj_mega(
    const short* __restrict__ qb, const short* __restrict__ eb,
    const short* __restrict__ wsb, const short* __restrict__ whb,
    const short* __restrict__ wob, const int* __restrict__ slen,
    float* __restrict__ qe, float* __restrict__ ke,
    short* __restrict__ ewt, float* __restrict__ qw) {
    const int job = blockIdx.x;
    const int lane = threadIdx.x;
    const int r = lane & 15, kb = lane >> 4;
    const short* A; int lda;
    const short* W; int ldw;
    int epi;            // 0 = f32 exp2(acc*QKS), 1 = bf16 plain, 2 = f32 plain
    float* Cf = nullptr; short* Cb = nullptr; int ldc;
    if (job < 256) {
        const int m0 = (job >> 4) * 32, n0 = (job & 15) * 32;
        A = qb + (size_t)m0 * H; lda = H;
        W = wsb + (size_t)n0 * H; ldw = H;
        Cf = qe + (size_t)m0 * H + n0; ldc = H; epi = 0;
    } else if (job < 1280) {
        const int j = job - 256;
        const int m0 = (j >> 4) * 32, n0 = (j & 15) * 32;
        if ((m0 & 511) >= slen[m0 >> 9]) return;   // fully-masked k-tile
        A = eb + (size_t)m0 * H; lda = H;
        W = whb + (size_t)n0 * H; ldw = H;
        Cf = ke + (size_t)m0 * H + n0; ldc = H; epi = 0;
    } else if (job < 2304) {
        const int j = job - 1280;
        const int b = j >> 8;
        const int m0 = ((j >> 4) & 15) * 32;       // o
        const int n0 = (j & 15) * 32;              // s
        if (n0 >= slen[b]) return;                 // U==0 there, never read
        A = wob + (size_t)m0 * (2 * H); lda = 2 * H;              // Wo1 rows
        W = eb + ((size_t)b * S + n0) * H; ldw = H;               // enc_b rows
        Cb = ewt + (size_t)b * H * S + (size_t)m0 * S + n0; ldc = S; epi = 1;
    } else {
        const int j = job - 2304;
        const int m0 = (j >> 4) * 32, n0 = (j & 15) * 32;
        A = qb + (size_t)m0 * H; lda = H;
        W = wob + (size_t)n0 * (2 * H) + H; ldw = 2 * H;          // Wo2 rows
        Cf = qw + (size_t)m0 * H + n0; ldc = H; epi = 2;
    }
    const short* a0p = A + (size_t)r * lda + kb * 8;
    const short* a1p = a0p + (size_t)16 * lda;
    const short* b0p = W + (size_t)r * ldw + kb * 8;
    const short* b1p = b0p + (size_t)16 * ldw;
    f32x4 acc00 = {0,0,0,0}, acc01 = {0,0,0,0}, acc10 = {0,0,0,0}, acc11 = {0,0,0,0};
#pragma unroll 4
    for (int k = 0; k < H; k += 32) {
        bf16x8 a0 = *(const bf16x8*)(a0p + k);
        bf16x8 a1 = *(const bf16x8*)(a1p + k);
        bf16x8 b0 = *(const bf16x8*)(b0p + k);
        bf16x8 b1 = *(const bf16x8*)(b1p + k);
        acc00 = __builtin_amdgcn_mfma_f32_16x16x32_bf16(a0, b0, acc00, 0, 0, 0);
        acc01 = __builtin_amdgcn_mfma_f32_16x16x32_bf16(a0, b1, acc01, 0, 0, 0);
        acc10 = __builtin_amdgcn_mfma_f32_16x16x32_bf16(a1, b0, acc10, 0, 0, 0);
        acc11 = __builtin_amdgcn_mfma_f32_16x16x32_bf16(a1, b1, acc11, 0, 0, 0);
    }
    const int cr = kb * 4, cc = r;
    if (epi == 0) {
#pragma unroll
        for (int g = 0; g < 4; ++g) {
            Cf[(size_t)(cr + g) * ldc + cc]           = EXP2F(acc00[g] * QK_SCALE);
            Cf[(size_t)(cr + g) * ldc + 16 + cc]      = EXP2F(acc01[g] * QK_SCALE);
            Cf[(size_t)(16 + cr + g) * ldc + cc]      = EXP2F(acc10[g] * QK_SCALE);
            Cf[(size_t)(16 + cr + g) * ldc + 16 + cc] = EXP2F(acc11[g] * QK_SCALE);
        }
    } else if (epi == 1) {
#pragma unroll
        for (int g = 0; g < 4; ++g) {
            Cb[(size_t)(cr + g) * ldc + cc]           = f2b(acc00[g]);
            Cb[(size_t)(cr + g) * ldc + 16 + cc]      = f2b(acc01[g]);
            Cb[(size_t)(16 + cr + g) * ldc + cc]      = f2b(acc10[g]);
            Cb[(size_t)(16 + cr + g) * ldc + 16 + cc] = f2b(acc11[g]);
        }
    } else {
#pragma unroll
        for (int g = 0; g < 4; ++g) {
            Cf[(size_t)(cr + g) * ldc + cc]           = acc00[g];
            Cf[(size_t)(cr + g) * ldc + 16 + cc]      = acc01[g];
            Cf[(size_t)(16 + cr + g) * ldc + cc]      = acc10[g];
            Cf[(size_t)(16 + cr + g) * ldc + 16 + cc] = acc11[g];
        }
    }
}

// ---- phase 3: score quarters, lane-per-s structure ----
// scoreh[qt][b*T+t][s] = -sum_h 2 v[h] * rcp(Eq[t,h]*Ek[s,h] + 1)
// Wave: 64 s (one per lane) x 4 t x 128 h. k lane-private in REGISTERS
// (two 64-h passes of 16 float4); q/v lane-uniform LDS broadcasts.
// LDS traffic ~0.02 B/elem (was ~3 B/elem in v4 -> LDS-BW-bound at ~25 us).
__global__ __launch_bounds__(64) void score_v6(
    const float* __restrict__ qe, const float* __restrict__ ke,
    const float* __restrict__ v, const int* __restrict__ slen,
    float* __restrict__ scoreh) {
    const int qt = blockIdx.z & 3;
    const int b = blockIdx.z >> 2;
    const int L = slen[b];
    const int sbase = blockIdx.x * 64;
    if (sbase >= L) return;
    const int t0 = blockIdx.y * 4;
    const int hbase = qt * 128;
    __shared__ __align__(16) float qs[4][132];
    __shared__ __align__(16) float vsh[132];
    const int lane = threadIdx.x;
    {   // stage q rows t0..t0+3 (128 h each) + v (negated, x2)
        const int tr = lane >> 4, c = (lane & 15) * 8;
        const float* qsrc = qe + (size_t)(b * T + t0 + tr) * H + hbase + c;
        *(float4*)&qs[tr][c]     = *(const float4*)qsrc;
        *(float4*)&qs[tr][c + 4] = *(const float4*)(qsrc + 4);
        if (lane < 32) {
            float4 vv = *(const float4*)&v[hbase + lane * 4];
            *(float4*)&vsh[lane * 4] =
                make_float4(-2.f * vv.x, -2.f * vv.y, -2.f * vv.z, -2.f * vv.w);
        }
    }
    __syncthreads();
    const float* krow = ke + (size_t)(b * S + sbase + lane) * H + hbase;
    float acc0 = 0.f, acc1 = 0.f, acc2 = 0.f, acc3 = 0.f;
#pragma unroll
    for (int chunk = 0; chunk < 2; ++chunk) {
        const int ho = chunk * 64;
        float4 kv[16];
#pragma unroll
        for (int j = 0; j < 16; ++j)
            kv[j] = *(const float4*)(krow + ho + j * 4);   // lane-private k regs
#pragma unroll
        for (int j = 0; j < 16; ++j) {
            float4 v4 = *(const float4*)&vsh[ho + j * 4];         // broadcast
            float4 q0 = *(const float4*)&qs[0][ho + j * 4];       // broadcast
            float4 q1 = *(const float4*)&qs[1][ho + j * 4];
            float4 q2 = *(const float4*)&qs[2][ho + j * 4];
            float4 q3 = *(const float4*)&qs[3][ho + j * 4];
            acc0 = fmaf(v4.x, __builtin_amdgcn_rcpf(fmaf(q0.x, kv[j].x, 1.f)), acc0);
            acc1 = fmaf(v4.x, __builtin_amdgcn_rcpf(fmaf(q1.x, kv[j].x, 1.f)), acc1);
            acc2 = fmaf(v4.x, __builtin_amdgcn_rcpf(fmaf(q2.x, kv[j].x, 1.f)), acc2);
            acc3 = fmaf(v4.x, __builtin_amdgcn_rcpf(fmaf(q3.x, kv[j].x, 1.f)), acc3);
            acc0 = fmaf(v4.y, __builtin_amdgcn_rcpf(fmaf(q0.y, kv[j].y, 1.f)), acc0);
            acc1 = fmaf(v4.y, __builtin_amdgcn_rcpf(fmaf(q1.y, kv[j].y, 1.f)), acc1);
            acc2 = fmaf(v4.y, __builtin_amdgcn_rcpf(fmaf(q2.y, kv[j].y, 1.f)), acc2);
            acc3 = fmaf(v4.y, __builtin_amdgcn_rcpf(fmaf(q3.y, kv[j].y, 1.f)), acc3);
            acc0 = fmaf(v4.z, __builtin_amdgcn_rcpf(fmaf(q0.z, kv[j].z, 1.f)), acc0);
            acc1 = fmaf(v4.z, __builtin_amdgcn_rcpf(fmaf(q1.z, kv[j].z, 1.f)), acc1);
            acc2 = fmaf(v4.z, __builtin_amdgcn_rcpf(fmaf(q2.z, kv[j].z, 1.f)), acc2);
            acc3 = fmaf(v4.z, __builtin_amdgcn_rcpf(fmaf(q3.z, kv[j].z, 1.f)), acc3);
            acc0 = fmaf(v4.w, __builtin_amdgcn_rcpf(fmaf(q0.w, kv[j].w, 1.f)), acc0);
            acc1 = fmaf(v4.w, __builtin_amdgcn_rcpf(fmaf(q1.w, kv[j].w, 1.f)), acc1);
            acc2 = fmaf(v4.w, __builtin_amdgcn_rcpf(fmaf(q2.w, kv[j].w, 1.f)), acc2);
            acc3 = fmaf(v4.w, __builtin_amdgcn_rcpf(fmaf(q3.w, kv[j].w, 1.f)), acc3);
        }
    }
    const size_t obase = ((size_t)qt * (B * T) + b * T + t0) * S + sbase + lane;
    scoreh[obase]         = acc0;
    scoreh[obase + S]     = acc1;
    scoreh[obase + 2 * S] = acc2;
    scoreh[obase + 3 * S] = acc3;
}

// ---- phase 4: combine quarters -> U = bf16(exp(score')) + Z[row] ----
// |score'| <= 2*sum|v| ~ 8 -> exp is overflow-safe WITHOUT max-shift.
__global__ __launch_bounds__(256) void combine_k(
    const float* __restrict__ scoreh, const int* __restrict__ slen,
    short* __restrict__ U, float* __restrict__ Z) {
    const int row = blockIdx.x * 4 + (threadIdx.x >> 6);
    const int lane = threadIdx.x & 63;
    const int L = slen[row >> 7];
    const size_t sl = (size_t)(B * T) * S;
    const float* p = scoreh + (size_t)row * S + lane * 8;
    float e[8];
    float sm = 0.f;
#pragma unroll
    for (int j = 0; j < 2; ++j) {
        float4 q0 = *(const float4*)(p + j * 4);
        float4 q1 = *(const float4*)(p + sl + j * 4);
        float4 q2 = *(const float4*)(p + 2 * sl + j * 4);
        float4 q3 = *(const float4*)(p + 3 * sl + j * 4);
        e[j * 4 + 0] = __expf(q0.x + q1.x + q2.x + q3.x);
        e[j * 4 + 1] = __expf(q0.y + q1.y + q2.y + q3.y);
        e[j * 4 + 2] = __expf(q0.z + q1.z + q2.z + q3.z);
        e[j * 4 + 3] = __expf(q0.w + q1.w + q2.w + q3.w);
    }
    const int cbase = lane * 8;
#pragma unroll
    for (int j = 0; j < 8; ++j) {
        if (cbase + j >= L) e[j] = 0.f;   // masked (incl. straddle garbage)
        sm += e[j];
    }
#pragma unroll
    for (int off = 1; off < 64; off <<= 1) sm += __shfl_xor(sm, off);
    if (lane == 0) Z[row] = sm;
    short* o = U + (size_t)row * S + cbase;
    ushort4 u0 = make_ushort4((unsigned short)f2b(e[0]), (unsigned short)f2b(e[1]),
                              (unsigned short)f2b(e[2]), (unsigned short)f2b(e[3]));
    ushort4 u1 = make_ushort4((unsigned short)f2b(e[4]), (unsigned short)f2b(e[5]),
                              (unsigned short)f2b(e[6]), (unsigned short)f2b(e[7]));
    *(ushort4*)o = u0;
    *(ushort4*)(o + 4) = u1;
}

// ---- phase 5: pre = tanh((U @ EWT)/Z + QW + bias)  (K capped at ceil32(L)) ----
__global__ __launch_bounds__(64) void mfma_out2(
    const short* __restrict__ U, const short* __restrict__ ewt,
    const float* __restrict__ qw, const float* __restrict__ Z,
    const int* __restrict__ slen, const float* __restrict__ bias,
    float* __restrict__ pre) {
    const int lane = threadIdx.x;
    const int r = lane & 15, kb = lane >> 4;
    const int m0 = blockIdx.y * 32;        // t-rows
    const int n0 = blockIdx.x * 32;        // o-cols
    const int b = m0 >> 7;
    const int L = slen[b];
    const int Keff = min(S, (L + 31) & ~31);
    const short* A = U + (size_t)m0 * S;
    const short* Bp = ewt + (size_t)b * H * S;
    const short* a0p = A + (size_t)r * S + kb * 8;
    const short* a1p = a0p + 16 * S;
    const short* b0p = Bp + (size_t)(n0 + r) * S + kb * 8;
    const short* b1p = b0p + 16 * S;
    f32x4 acc00 = {0,0,0,0}, acc01 = {0,0,0,0}, acc10 = {0,0,0,0}, acc11 = {0,0,0,0};
#pragma unroll 2
    for (int k = 0; k < Keff; k += 32) {
        bf16x8 a0 = *(const bf16x8*)(a0p + k);
        bf16x8 a1 = *(const bf16x8*)(a1p + k);
        bf16x8 b0 = *(const bf16x8*)(b0p + k);
        bf16x8 b1 = *(const bf16x8*)(b1p + k);
        acc00 = __builtin_amdgcn_mfma_f32_16x16x32_bf16(a0, b0, acc00, 0, 0, 0);
        acc01 = __builtin_amdgcn_mfma_f32_16x16x32_bf16(a0, b1, acc01, 0, 0, 0);
        acc10 = __builtin_amdgcn_mfma_f32_16x16x32_bf16(a1, b0, acc10, 0, 0, 0);
        acc11 = __builtin_amdgcn_mfma_f32_16x16x32_bf16(a1, b1, acc11, 0, 0, 0);
    }
    const int cr = kb * 4, cc = r;
    float bn0 = bias[n0 + cc], bn1 = bias[n0 + 16 + cc];
#pragma unroll
    for (int g = 0; g < 4; ++g) {
        const int gr0 = m0 + cr + g;
        const int gr1 = gr0 + 16;
        float iz0 = __builtin_amdgcn_rcpf(Z[gr0]);
        float iz1 = __builtin_amdgcn_rcpf(Z[gr1]);
        size_t row0 = (size_t)gr0 * H;
        size_t row1 = (size_t)gr1 * H;
        pre[row0 + n0 + cc]      = fast_tanh(fmaf(acc00[g], iz0, qw[row0 + n0 + cc]) + bn0);
        pre[row0 + n0 + 16 + cc] = fast_tanh(fmaf(acc01[g], iz0, qw[row0 + n0 + 16 + cc]) + bn1);
        pre[row1 + n0 + cc]      = fast_tanh(fmaf(acc10[g], iz1, qw[row1 + n0 + cc]) + bn0);
        pre[row1 + n0 + 16 + cc] = fast_tanh(fmaf(acc11[g], iz1, qw[row1 + n0 + 16 + cc]) + bn1);
    }
}

// ---- phase 6: per-row LayerNorm ----
__global__ __launch_bounds__(256) void ln_out(
    const float* __restrict__ X, const float* __restrict__ gamma,
    const float* __restrict__ beta, float* __restrict__ out) {
    __shared__ float red[8];
    const int r = blockIdx.x;
    const int tid = threadIdx.x;
    const int lane = tid & 63, wv = tid >> 6;
    const float* x = X + (size_t)r * H;
    float x0 = x[tid], x1 = x[tid + 256];
    float s = x0 + x1;
#pragma unroll
    for (int off = 32; off > 0; off >>= 1) s += __shfl_down(s, off);
    if (lane == 0) red[wv] = s;
    __syncthreads();
    float mu = (red[0] + red[1] + red[2] + red[3]) * (1.0f / H);
    float d0 = x0 - mu, d1 = x1 - mu;
    float vsum = d0 * d0 + d1 * d1;
#pragma unroll
    for (int off = 32; off > 0; off >>= 1) vsum += __shfl_down(vsum, off);
    if (lane == 0) red[4 + wv] = vsum;
    __syncthreads();
    float var = (red[4] + red[5] + red[6] + red[7]) * (1.0f / H);
    float inv = rsqrtf(var + 1e-5f);
    out[(size_t)r * H + tid] = d0 * inv * gamma[tid] + beta[tid];
    out[(size_t)r * H + tid + 256] = d1 * inv * gamma[tid + 256] + beta[tid + 256];
}

extern "C" void kernel_launch(void* const* d_in, const int* in_sizes, int n_in,
                              void* d_out, int out_size, void* d_ws, size_t ws_size,
                              hipStream_t stream) {
    const float* query = (const float*)d_in[0];
    const float* enc   = (const float*)d_in[1];
    const int*   slen  = (const int*)d_in[2];
    const float* W_h   = (const float*)d_in[3];
    const float* W_s   = (const float*)d_in[4];
    const float* v     = (const float*)d_in[5];
    const float* W_out = (const float*)d_in[6];
    const float* b_out = (const float*)d_in[7];
    const float* gamma = (const float*)d_in[8];
    const float* beta  = (const float*)d_in[9];
    float* out = (float*)d_out;

    // ---- workspace map, non-aliased (d_ws = 256 MB) ----
    char* base = (char*)d_ws;
    short* qb     = (short*)(base + 0x000000);   // 512K bf16 query
    short* wsb    = (short*)(base + 0x080000);   // 512K bf16 W_s
    short* whb    = (short*)(base + 0x100000);   // 512K bf16 W_h
    short* wob    = (short*)(base + 0x180000);   // 1M   bf16 W_out
    short* eb     = (short*)(base + 0x280000);   // 2M   bf16 enc
    float* qe     = (float*)(base + 0x480000);   // 1M   f32 Eq
    float* ke     = (float*)(base + 0x580000);   // 4M   f32 Ek
    float* scoreh = (float*)(base + 0x980000);   // 4M   f32 score quarters
    short* U      = (short*)(base + 0xD80000);   // 512K bf16 unnormalized attn
    short* ewt    = (short*)(base + 0xE00000);   // 2M   bf16 enc@Wo1 (per-b [o][s])
    float* qw     = (float*)(base + 0x1000000);  // 1M   f32 q@Wo2^T
    float* Z      = (float*)(base + 0x1100000);  // 2K   f32 row normalizers
    float* pre    = (float*)(base + 0x1101000);  // 1M   f32 pre-LN

    cvt_all<<<dim3(1152), dim3(256), 0, stream>>>(query, W_s, W_h, W_out, enc,
                                                  qb, wsb, whb, wob, eb);
    proj_mega<<<dim3(2560), dim3(64), 0, stream>>>(qb, eb, wsb, whb, wob, slen,
                                                   qe, ke, ewt, qw);
    // score quarters: grid (s-chunks=8, t-groups=32, b*4 quarters=16)
    score_v6<<<dim3(8, 32, 16), dim3(64), 0, stream>>>(qe, ke, v, slen, scoreh);
    combine_k<<<dim3(128), dim3(256), 0, stream>>>(scoreh, slen, U, Z);
    mfma_out2<<<dim3(16, 16), dim3(64), 0, stream>>>(U, ewt, qw, Z, slen, b_out, pre);
    ln_out<<<dim3(B * T), dim3(256), 0, stream>>>(pre, gamma, beta, out);
}

// Round 15
// 62.509 us; speedup vs baseline: 1.1366x; 1.1366x over previous
//
#include <hip/hip_runtime.h>
#include <hip/hip_bf16.h>
#include <math.h>

#define B 4
#define T 128
#define S 512
#define H 512
// 2*log2(e): folds tanh's 2x and e->2 base change into the projection epilogue
#define QK_SCALE 2.8853900817779268f

// Hardware exp2 (v_exp_f32). Fallback = native exp path, never OCML-precise.
#if defined(__has_builtin)
#if __has_builtin(__builtin_amdgcn_exp2f)
#define EXP2F(x) __builtin_amdgcn_exp2f(x)
#else
#define EXP2F(x) __expf((x) * 0.6931471805599453f)
#endif
#else
#define EXP2F(x) __expf((x) * 0.6931471805599453f)
#endif

typedef __attribute__((ext_vector_type(8))) short bf16x8;
typedef __attribute__((ext_vector_type(4))) float f32x4;

__device__ __forceinline__ short f2b(float x) {   // f32 -> bf16 RNE
    unsigned int u = __float_as_uint(x);
    u += 0x7fffu + ((u >> 16) & 1u);
    return (short)(u >> 16);
}
__device__ __forceinline__ float fast_tanh(float x) {
    float e = __expf(2.0f * x);
    float r = __builtin_amdgcn_rcpf(e + 1.0f);
    return 1.0f - 2.0f * r;
}

// ---- phase 1: cvt inputs to bf16 (1152 blocks) ----
__global__ __launch_bounds__(256) void cvt_all(
    const float* __restrict__ q, const float* __restrict__ Ws,
    const float* __restrict__ Wh, const float* __restrict__ Wo,
    const float* __restrict__ enc,
    short* __restrict__ qb, short* __restrict__ wsb, short* __restrict__ whb,
    short* __restrict__ wob, short* __restrict__ eb) {
    size_t i = ((size_t)blockIdx.x * 256 + threadIdx.x) * 8;
    const float* src; short* dst; size_t off;
    if (i < 262144)        { src = q;   dst = qb;  off = i; }
    else if (i < 524288)   { src = Ws;  dst = wsb; off = i - 262144; }
    else if (i < 786432)   { src = Wh;  dst = whb; off = i - 524288; }
    else if (i < 1310720)  { src = Wo;  dst = wob; off = i - 786432; }
    else                   { src = enc; dst = eb;  off = i - 1310720; }
    float4 a = *(const float4*)(src + off);
    float4 b = *(const float4*)(src + off + 4);
    ushort4 o0 = make_ushort4((unsigned short)f2b(a.x), (unsigned short)f2b(a.y),
                              (unsigned short)f2b(a.z), (unsigned short)f2b(a.w));
    ushort4 o1 = make_ushort4((unsigned short)f2b(b.x), (unsigned short)f2b(b.y),
                              (unsigned short)f2b(b.z), (unsigned short)f2b(b.w));
    *(ushort4*)(dst + off) = o0;
    *(ushort4*)(dst + off + 4) = o1;
}

// ---- phase 2: mega wave-GEMM: 2560 one-wave 32x32 jobs ----
//   jobs [0,256):     Eq[t][h] = exp2(q@Ws^T * QKS)      -> qe   (f32, row-major)
//   jobs [256,1280):  EkT[b][h][s] = exp2(enc@Wh^T *QKS) -> keT  (f32, TRANSPOSED) [masked skip]
//   jobs [1280,2304): EWT[b][o][s] = bf16(Wo1@enc_b^T)   -> ewt  (bf16) [masked s-tiles skip]
//   jobs [2304,2560): QW = q@Wo2^T                       -> qw   (f32)
// keT transpose is free here: C-fragment rows (cr+g, g=0..3) for fixed col cc
// are contiguous along s in [h][s] layout -> float4 stores.
__global__ __launch_bounds__(64) void proj_mega(
    const short* __restrict__ qb, const short* __restrict__ eb,
    const short* __restrict__ wsb, const short* __restrict__ whb,
    const short* __restrict__ wob, const int* __restrict__ slen,
    float* __restrict__ qe, float* __restrict__ keT,
    short* __restrict__ ewt, float* __restrict__ qw) {
    const int job = blockIdx.x;
    const int lane = threadIdx.x;
    const int r = lane & 15, kb = lane >> 4;
    const short* A; int lda;
    const short* W; int ldw;
    int epi;            // 0 = f32 exp2 row-major, 1 = bf16 plain, 2 = f32 plain, 3 = keT
    float* Cf = nullptr; short* Cb = nullptr; int ldc;
    int bT = 0, m0T = 0, n0T = 0;
    if (job < 256) {
        const int m0 = (job >> 4) * 32, n0 = (job & 15) * 32;
        A = qb + (size_t)m0 * H; lda = H;
        W = wsb + (size_t)n0 * H; ldw = H;
        Cf = qe + (size_t)m0 * H + n0; ldc = H; epi = 0;
    } else if (job < 1280) {
        const int j = job - 256;
        const int m0 = (j >> 4) * 32, n0 = (j & 15) * 32;
        if ((m0 & 511) >= slen[m0 >> 9]) return;   // fully-masked k-tile
        A = eb + (size_t)m0 * H; lda = H;
        W = whb + (size_t)n0 * H; ldw = H;
        epi = 3; bT = m0 >> 9; m0T = m0 & 511; n0T = n0;
    } else if (job < 2304) {
        const int j = job - 1280;
        const int b = j >> 8;
        const int m0 = ((j >> 4) & 15) * 32;       // o
        const int n0 = (j & 15) * 32;              // s
        if (n0 >= slen[b]) return;                 // U==0 there, never read
        A = wob + (size_t)m0 * (2 * H); lda = 2 * H;              // Wo1 rows
        W = eb + ((size_t)b * S + n0) * H; ldw = H;               // enc_b rows
        Cb = ewt + (size_t)b * H * S + (size_t)m0 * S + n0; ldc = S; epi = 1;
    } else {
        const int j = job - 2304;
        const int m0 = (j >> 4) * 32, n0 = (j & 15) * 32;
        A = qb + (size_t)m0 * H; lda = H;
        W = wob + (size_t)n0 * (2 * H) + H; ldw = 2 * H;          // Wo2 rows
        Cf = qw + (size_t)m0 * H + n0; ldc = H; epi = 2;
    }
    const short* a0p = A + (size_t)r * lda + kb * 8;
    const short* a1p = a0p + (size_t)16 * lda;
    const short* b0p = W + (size_t)r * ldw + kb * 8;
    const short* b1p = b0p + (size_t)16 * ldw;
    f32x4 acc00 = {0,0,0,0}, acc01 = {0,0,0,0}, acc10 = {0,0,0,0}, acc11 = {0,0,0,0};
#pragma unroll 4
    for (int k = 0; k < H; k += 32) {
        bf16x8 a0 = *(const bf16x8*)(a0p + k);
        bf16x8 a1 = *(const bf16x8*)(a1p + k);
        bf16x8 b0 = *(const bf16x8*)(b0p + k);
        bf16x8 b1 = *(const bf16x8*)(b1p + k);
        acc00 = __builtin_amdgcn_mfma_f32_16x16x32_bf16(a0, b0, acc00, 0, 0, 0);
        acc01 = __builtin_amdgcn_mfma_f32_16x16x32_bf16(a0, b1, acc01, 0, 0, 0);
        acc10 = __builtin_amdgcn_mfma_f32_16x16x32_bf16(a1, b0, acc10, 0, 0, 0);
        acc11 = __builtin_amdgcn_mfma_f32_16x16x32_bf16(a1, b1, acc11, 0, 0, 0);
    }
    const int cr = kb * 4, cc = r;
    if (epi == 3) {   // keT[b][h][s]: rows cr+g contiguous along s -> float4 stores
        float* base = keT + ((size_t)bT * H + n0T + cc) * S + m0T + cr;
        float4 w00 = make_float4(EXP2F(acc00[0] * QK_SCALE), EXP2F(acc00[1] * QK_SCALE),
                                 EXP2F(acc00[2] * QK_SCALE), EXP2F(acc00[3] * QK_SCALE));
        float4 w01 = make_float4(EXP2F(acc01[0] * QK_SCALE), EXP2F(acc01[1] * QK_SCALE),
                                 EXP2F(acc01[2] * QK_SCALE), EXP2F(acc01[3] * QK_SCALE));
        float4 w10 = make_float4(EXP2F(acc10[0] * QK_SCALE), EXP2F(acc10[1] * QK_SCALE),
                                 EXP2F(acc10[2] * QK_SCALE), EXP2F(acc10[3] * QK_SCALE));
        float4 w11 = make_float4(EXP2F(acc11[0] * QK_SCALE), EXP2F(acc11[1] * QK_SCALE),
                                 EXP2F(acc11[2] * QK_SCALE), EXP2F(acc11[3] * QK_SCALE));
        *(float4*)base              = w00;   // (h=n0+cc,    s=m0+cr..+3)
        *(float4*)(base + 16 * S)   = w01;   // (h=n0+16+cc, s=m0+cr..+3)
        *(float4*)(base + 16)       = w10;   // (h=n0+cc,    s=m0+16+cr..)
        *(float4*)(base + 16 * S + 16) = w11;
    } else if (epi == 0) {
#pragma unroll
        for (int g = 0; g < 4; ++g) {
            Cf[(size_t)(cr + g) * ldc + cc]           = EXP2F(acc00[g] * QK_SCALE);
            Cf[(size_t)(cr + g) * ldc + 16 + cc]      = EXP2F(acc01[g] * QK_SCALE);
            Cf[(size_t)(16 + cr + g) * ldc + cc]      = EXP2F(acc10[g] * QK_SCALE);
            Cf[(size_t)(16 + cr + g) * ldc + 16 + cc] = EXP2F(acc11[g] * QK_SCALE);
        }
    } else if (epi == 1) {
#pragma unroll
        for (int g = 0; g < 4; ++g) {
            Cb[(size_t)(cr + g) * ldc + cc]           = f2b(acc00[g]);
            Cb[(size_t)(cr + g) * ldc + 16 + cc]      = f2b(acc01[g]);
            Cb[(size_t)(16 + cr + g) * ldc + cc]      = f2b(acc10[g]);
            Cb[(size_t)(16 + cr + g) * ldc + 16 + cc] = f2b(acc11[g]);
        }
    } else {
#pragma unroll
        for (int g = 0; g < 4; ++g) {
            Cf[(size_t)(cr + g) * ldc + cc]           = acc00[g];
            Cf[(size_t)(cr + g) * ldc + 16 + cc]      = acc01[g];
            Cf[(size_t)(16 + cr + g) * ldc + cc]      = acc10[g];
            Cf[(size_t)(16 + cr + g) * ldc + 16 + cc] = acc11[g];
        }
    }
}

// ---- phase 3: score quarters, lane-per-s with TRANSPOSED keT ----
// scoreh[qt][b*T+t][s] = -sum_h 2 v[h] * rcp(Eq[t,h]*EkT[h,s] + 1)
// lane = s -> keT loads are fully coalesced dwords (64 consecutive s);
// q/v are lane-uniform LDS broadcasts (conflict-free). 4 t-rows per wave.
__global__ __launch_bounds__(64) void score_v7(
    const float* __restrict__ qe, const float* __restrict__ keT,
    const float* __restrict__ v, const int* __restrict__ slen,
    float* __restrict__ scoreh) {
    const int qt = blockIdx.z & 3;
    const int b = blockIdx.z >> 2;
    const int L = slen[b];
    const int sbase = blockIdx.x * 64;
    if (sbase >= L) return;
    const int t0 = blockIdx.y * 4;
    const int hbase = qt * 128;
    __shared__ __align__(16) float qs[4][132];
    __shared__ __align__(16) float vsh[128];
    const int lane = threadIdx.x;
    {   // stage q rows t0..t0+3 (128 h each) + v (negated, x2)
        const int tr = lane >> 4, c = (lane & 15) * 8;
        const float* qsrc = qe + (size_t)(b * T + t0 + tr) * H + hbase + c;
        *(float4*)&qs[tr][c]     = *(const float4*)qsrc;
        *(float4*)&qs[tr][c + 4] = *(const float4*)(qsrc + 4);
        if (lane < 32) {
            float4 vv = *(const float4*)&v[hbase + lane * 4];
            *(float4*)&vsh[lane * 4] =
                make_float4(-2.f * vv.x, -2.f * vv.y, -2.f * vv.z, -2.f * vv.w);
        }
    }
    __syncthreads();
    const float* kcol = keT + ((size_t)b * H + hbase) * S + sbase + lane;
    float acc0 = 0.f, acc1 = 0.f, acc2 = 0.f, acc3 = 0.f;
#pragma unroll 8
    for (int h = 0; h < 128; ++h) {
        float kv = kcol[(size_t)h * S];   // coalesced: 64 consecutive s
        float vh = vsh[h];                // broadcasts
        float q0 = qs[0][h], q1 = qs[1][h], q2 = qs[2][h], q3 = qs[3][h];
        acc0 = fmaf(vh, __builtin_amdgcn_rcpf(fmaf(q0, kv, 1.f)), acc0);
        acc1 = fmaf(vh, __builtin_amdgcn_rcpf(fmaf(q1, kv, 1.f)), acc1);
        acc2 = fmaf(vh, __builtin_amdgcn_rcpf(fmaf(q2, kv, 1.f)), acc2);
        acc3 = fmaf(vh, __builtin_amdgcn_rcpf(fmaf(q3, kv, 1.f)), acc3);
    }
    const size_t obase = ((size_t)qt * (B * T) + b * T + t0) * S + sbase + lane;
    scoreh[obase]         = acc0;
    scoreh[obase + S]     = acc1;
    scoreh[obase + 2 * S] = acc2;
    scoreh[obase + 3 * S] = acc3;
}

// ---- phase 4: combine quarters -> U = bf16(exp(score')) + Z[row] ----
// |score'| <= 2*sum|v| ~ 8 -> exp is overflow-safe WITHOUT max-shift.
__global__ __launch_bounds__(256) void combine_k(
    const float* __restrict__ scoreh, const int* __restrict__ slen,
    short* __restrict__ U, float* __restrict__ Z) {
    const int row = blockIdx.x * 4 + (threadIdx.x >> 6);
    const int lane = threadIdx.x & 63;
    const int L = slen[row >> 7];
    const size_t sl = (size_t)(B * T) * S;
    const float* p = scoreh + (size_t)row * S + lane * 8;
    float e[8];
    float sm = 0.f;
#pragma unroll
    for (int j = 0; j < 2; ++j) {
        float4 q0 = *(const float4*)(p + j * 4);
        float4 q1 = *(const float4*)(p + sl + j * 4);
        float4 q2 = *(const float4*)(p + 2 * sl + j * 4);
        float4 q3 = *(const float4*)(p + 3 * sl + j * 4);
        e[j * 4 + 0] = __expf(q0.x + q1.x + q2.x + q3.x);
        e[j * 4 + 1] = __expf(q0.y + q1.y + q2.y + q3.y);
        e[j * 4 + 2] = __expf(q0.z + q1.z + q2.z + q3.z);
        e[j * 4 + 3] = __expf(q0.w + q1.w + q2.w + q3.w);
    }
    const int cbase = lane * 8;
#pragma unroll
    for (int j = 0; j < 8; ++j) {
        if (cbase + j >= L) e[j] = 0.f;   // masked (incl. straddle garbage)
        sm += e[j];
    }
#pragma unroll
    for (int off = 1; off < 64; off <<= 1) sm += __shfl_xor(sm, off);
    if (lane == 0) Z[row] = sm;
    short* o = U + (size_t)row * S + cbase;
    ushort4 u0 = make_ushort4((unsigned short)f2b(e[0]), (unsigned short)f2b(e[1]),
                              (unsigned short)f2b(e[2]), (unsigned short)f2b(e[3]));
    ushort4 u1 = make_ushort4((unsigned short)f2b(e[4]), (unsigned short)f2b(e[5]),
                              (unsigned short)f2b(e[6]), (unsigned short)f2b(e[7]));
    *(ushort4*)o = u0;
    *(ushort4*)(o + 4) = u1;
}

// ---- phase 5: pre = tanh((U @ EWT)/Z + QW + bias)  (K capped at ceil32(L)) ----
__global__ __launch_bounds__(64) void mfma_out2(
    const short* __restrict__ U, const short* __restrict__ ewt,
    const float* __restrict__ qw, const float* __restrict__ Z,
    const int* __restrict__ slen, const float* __restrict__ bias,
    float* __restrict__ pre) {
    const int lane = threadIdx.x;
    const int r = lane & 15, kb = lane >> 4;
    const int m0 = blockIdx.y * 32;        // t-rows
    const int n0 = blockIdx.x * 32;        // o-cols
    const int b = m0 >> 7;
    const int L = slen[b];
    const int Keff = min(S, (L + 31) & ~31);
    const short* A = U + (size_t)m0 * S;
    const short* Bp = ewt + (size_t)b * H * S;
    const short* a0p = A + (size_t)r * S + kb * 8;
    const short* a1p = a0p + 16 * S;
    const short* b0p = Bp + (size_t)(n0 + r) * S + kb * 8;
    const short* b1p = b0p + 16 * S;
    f32x4 acc00 = {0,0,0,0}, acc01 = {0,0,0,0}, acc10 = {0,0,0,0}, acc11 = {0,0,0,0};
#pragma unroll 2
    for (int k = 0; k < Keff; k += 32) {
        bf16x8 a0 = *(const bf16x8*)(a0p + k);
        bf16x8 a1 = *(const bf16x8*)(a1p + k);
        bf16x8 b0 = *(const bf16x8*)(b0p + k);
        bf16x8 b1 = *(const bf16x8*)(b1p + k);
        acc00 = __builtin_amdgcn_mfma_f32_16x16x32_bf16(a0, b0, acc00, 0, 0, 0);
        acc01 = __builtin_amdgcn_mfma_f32_16x16x32_bf16(a0, b1, acc01, 0, 0, 0);
        acc10 = __builtin_amdgcn_mfma_f32_16x16x32_bf16(a1, b0, acc10, 0, 0, 0);
        acc11 = __builtin_amdgcn_mfma_f32_16x16x32_bf16(a1, b1, acc11, 0, 0, 0);
    }
    const int cr = kb * 4, cc = r;
    float bn0 = bias[n0 + cc], bn1 = bias[n0 + 16 + cc];
#pragma unroll
    for (int g = 0; g < 4; ++g) {
        const int gr0 = m0 + cr + g;
        const int gr1 = gr0 + 16;
        float iz0 = __builtin_amdgcn_rcpf(Z[gr0]);
        float iz1 = __builtin_amdgcn_rcpf(Z[gr1]);
        size_t row0 = (size_t)gr0 * H;
        size_t row1 = (size_t)gr1 * H;
        pre[row0 + n0 + cc]      = fast_tanh(fmaf(acc00[g], iz0, qw[row0 + n0 + cc]) + bn0);
        pre[row0 + n0 + 16 + cc] = fast_tanh(fmaf(acc01[g], iz0, qw[row0 + n0 + 16 + cc]) + bn1);
        pre[row1 + n0 + cc]      = fast_tanh(fmaf(acc10[g], iz1, qw[row1 + n0 + cc]) + bn0);
        pre[row1 + n0 + 16 + cc] = fast_tanh(fmaf(acc11[g], iz1, qw[row1 + n0 + 16 + cc]) + bn1);
    }
}

// ---- phase 6: per-row LayerNorm ----
__global__ __launch_bounds__(256) void ln_out(
    const float* __restrict__ X, const float* __restrict__ gamma,
    const float* __restrict__ beta, float* __restrict__ out) {
    __shared__ float red[8];
    const int r = blockIdx.x;
    const int tid = threadIdx.x;
    const int lane = tid & 63, wv = tid >> 6;
    const float* x = X + (size_t)r * H;
    float x0 = x[tid], x1 = x[tid + 256];
    float s = x0 + x1;
#pragma unroll
    for (int off = 32; off > 0; off >>= 1) s += __shfl_down(s, off);
    if (lane == 0) red[wv] = s;
    __syncthreads();
    float mu = (red[0] + red[1] + red[2] + red[3]) * (1.0f / H);
    float d0 = x0 - mu, d1 = x1 - mu;
    float vsum = d0 * d0 + d1 * d1;
#pragma unroll
    for (int off = 32; off > 0; off >>= 1) vsum += __shfl_down(vsum, off);
    if (lane == 0) red[4 + wv] = vsum;
    __syncthreads();
    float var = (red[4] + red[5] + red[6] + red[7]) * (1.0f / H);
    float inv = rsqrtf(var + 1e-5f);
    out[(size_t)r * H + tid] = d0 * inv * gamma[tid] + beta[tid];
    out[(size_t)r * H + tid + 256] = d1 * inv * gamma[tid + 256] + beta[tid + 256];
}

extern "C" void kernel_launch(void* const* d_in, const int* in_sizes, int n_in,
                              void* d_out, int out_size, void* d_ws, size_t ws_size,
                              hipStream_t stream) {
    const float* query = (const float*)d_in[0];
    const float* enc   = (const float*)d_in[1];
    const int*   slen  = (const int*)d_in[2];
    const float* W_h   = (const float*)d_in[3];
    const float* W_s   = (const float*)d_in[4];
    const float* v     = (const float*)d_in[5];
    const float* W_out = (const float*)d_in[6];
    const float* b_out = (const float*)d_in[7];
    const float* gamma = (const float*)d_in[8];
    const float* beta  = (const float*)d_in[9];
    float* out = (float*)d_out;

    // ---- workspace map, non-aliased (d_ws = 256 MB) ----
    char* base = (char*)d_ws;
    short* qb     = (short*)(base + 0x000000);   // 512K bf16 query
    short* wsb    = (short*)(base + 0x080000);   // 512K bf16 W_s
    short* whb    = (short*)(base + 0x100000);   // 512K bf16 W_h
    short* wob    = (short*)(base + 0x180000);   // 1M   bf16 W_out
    short* eb     = (short*)(base + 0x280000);   // 2M   bf16 enc
    float* qe     = (float*)(base + 0x480000);   // 1M   f32 Eq (row-major)
    float* keT    = (float*)(base + 0x580000);   // 4M   f32 EkT (per-b [h][s])
    float* scoreh = (float*)(base + 0x980000);   // 4M   f32 score quarters
    short* U      = (short*)(base + 0xD80000);   // 512K bf16 unnormalized attn
    short* ewt    = (short*)(base + 0xE00000);   // 2M   bf16 enc@Wo1 (per-b [o][s])
    float* qw     = (float*)(base + 0x1000000);  // 1M   f32 q@Wo2^T
    float* Z      = (float*)(base + 0x1100000);  // 2K   f32 row normalizers
    float* pre    = (float*)(base + 0x1101000);  // 1M   f32 pre-LN

    cvt_all<<<dim3(1152), dim3(256), 0, stream>>>(query, W_s, W_h, W_out, enc,
                                                  qb, wsb, whb, wob, eb);
    proj_mega<<<dim3(2560), dim3(64), 0, stream>>>(qb, eb, wsb, whb, wob, slen,
                                                   qe, keT, ewt, qw);
    // score quarters: grid (s-chunks=8, t-groups=32, b*4 quarters=16)
    score_v7<<<dim3(8, 32, 16), dim3(64), 0, stream>>>(qe, keT, v, slen, scoreh);
    combine_k<<<dim3(128), dim3(256), 0, stream>>>(scoreh, slen, U, Z);
    mfma_out2<<<dim3(16, 16), dim3(64), 0, stream>>>(U, ewt, qw, Z, slen, b_out, pre);
    ln_out<<<dim3(B * T), dim3(256), 0, stream>>>(pre, gamma, beta, out);
}